// Round 6
// baseline (1133.982 us; speedup 1.0000x reference)
//
#include <hip/hip_runtime.h>
#include <math.h>

#define NN 1024
#define MEM 300
#define SLICE 25       // j columns per column-slice block
#define GB 12          // column-slice blocks per (tree, node-group): 12*25 = 300
#define NG 16          // node-group parallelism per tree
#define BPT (GB * NG)  // blocks per tree = 192
#define SCAN_T 512

// ---------- agent-scope helpers (cross-XCD safe) ----------
__device__ __forceinline__ float agloadf(const float* p) {
  return __hip_atomic_load(p, __ATOMIC_RELAXED, __HIP_MEMORY_SCOPE_AGENT);
}
__device__ __forceinline__ void agstoref(float* p, float v) {
  __hip_atomic_store(p, v, __ATOMIC_RELAXED, __HIP_MEMORY_SCOPE_AGENT);
}

__device__ __forceinline__ float sigmoidf_(float x) {
  return 1.0f / (1.0f + expf(-x));
}

// ---------- K0: children CSR only (no levels needed: index order IS topological) ----------
__global__ __launch_bounds__(1024, 1)
void csr_kernel(const int* __restrict__ lparents, const int* __restrict__ rparents,
                int* __restrict__ childOff, int* __restrict__ childList) {
  const int t = blockIdx.x;
  const int* par = t ? rparents : lparents;
  const int n = threadIdx.x;
  __shared__ int aux[NN];
  __shared__ int coff[NN];
  __shared__ int chunk[32];
  const int p = par[n];
  aux[n] = 0;
  __syncthreads();
  if (n < NN - 1) atomicAdd(&aux[p], 1);
  __syncthreads();
  if (n < 32) { int s = 0; for (int i = 0; i < 32; ++i) s += aux[n * 32 + i]; chunk[n] = s; }
  __syncthreads();
  if (n == 0) { int acc = 0; for (int i = 0; i < 32; ++i) { int s = chunk[i]; chunk[i] = acc; acc += s; } }
  __syncthreads();
  if (n < 32) { int acc = chunk[n]; for (int i = 0; i < 32; ++i) { coff[n * 32 + i] = acc; acc += aux[n * 32 + i]; } }
  __syncthreads();
  childOff[t * (NN + 1) + n] = coff[n];
  if (n == 0) childOff[t * (NN + 1) + NN] = NN - 1;
  aux[n] = 0;
  __syncthreads();
  if (n < NN - 1) { int idx = coff[p] + atomicAdd(&aux[p], 1); childList[t * NN + idx] = n; }
}

// ---------- K1: x-projections ----------
#define K1_NT 32
#define K1_CT 48
__global__ __launch_bounds__(256, 1)
void proj_kernel(const int* __restrict__ lsent, const int* __restrict__ rsent,
                 const float* __restrict__ emb,
                 const float* __restrict__ Wioux, const float* __restrict__ bioux,
                 const float* __restrict__ Wfx, const float* __restrict__ bfx,
                 float* __restrict__ xiou, float* __restrict__ xf) {
  __shared__ float xt[K1_NT][300];
  __shared__ float wt[K1_CT][100];
  const int tid = threadIdx.x;
  const int g0 = blockIdx.y * K1_NT;
  const int c0 = blockIdx.x * K1_CT;

  for (int e = tid; e < K1_NT * 300; e += 256) {
    int nn = e / 300, k = e - nn * 300;
    int g = g0 + nn;
    int t = g >> 10, n = g & (NN - 1);
    int s = (t ? rsent : lsent)[n];
    xt[nn][k] = emb[(size_t)s * 300 + k];
  }

  const int a = tid >> 4;
  const int b = tid & 15;
  float acc00 = 0, acc01 = 0, acc02 = 0, acc10 = 0, acc11 = 0, acc12 = 0;

  for (int kc = 0; kc < 300; kc += 100) {
    __syncthreads();
    for (int e = tid; e < K1_CT * 100; e += 256) {
      int cc = e / 100, k = e - cc * 100;
      int col = c0 + cc;
      wt[cc][k] = (col < 900) ? Wioux[(size_t)col * 300 + kc + k]
                              : Wfx[(size_t)(col - 900) * 300 + kc + k];
    }
    __syncthreads();
    #pragma unroll
    for (int k4 = 0; k4 < 25; ++k4) {
      float4 x0 = *(const float4*)&xt[a][kc + k4 * 4];
      float4 x1 = *(const float4*)&xt[a + 16][kc + k4 * 4];
      float4 w0 = *(const float4*)&wt[b][k4 * 4];
      float4 w1 = *(const float4*)&wt[b + 16][k4 * 4];
      float4 w2 = *(const float4*)&wt[b + 32][k4 * 4];
      acc00 += x0.x * w0.x + x0.y * w0.y + x0.z * w0.z + x0.w * w0.w;
      acc01 += x0.x * w1.x + x0.y * w1.y + x0.z * w1.z + x0.w * w1.w;
      acc02 += x0.x * w2.x + x0.y * w2.y + x0.z * w2.z + x0.w * w2.w;
      acc10 += x1.x * w0.x + x1.y * w0.y + x1.z * w0.z + x1.w * w0.w;
      acc11 += x1.x * w1.x + x1.y * w1.y + x1.z * w1.z + x1.w * w1.w;
      acc12 += x1.x * w2.x + x1.y * w2.y + x1.z * w2.z + x1.w * w2.w;
    }
  }

  float accs[2][3] = {{acc00, acc01, acc02}, {acc10, acc11, acc12}};
  for (int ni = 0; ni < 2; ++ni) {
    for (int ci = 0; ci < 3; ++ci) {
      int g = g0 + a + 16 * ni;
      int col = c0 + b + 16 * ci;
      int t = g >> 10, n = g & (NN - 1);
      float v = accs[ni][ci];
      if (col < 900) xiou[((size_t)t * NN + n) * 900 + col] = v + bioux[col];
      else           xf[((size_t)t * NN + n) * 300 + (col - 900)] = v + bfx[col - 900];
    }
  }
}

// ---------- K2: barrier-free dataflow tree-LSTM ----------
// Each block owns (tree t, node-group gg, column-slice colb). It walks nodes
// n = gg, gg+NG, ... in increasing index order (parents[n]>n => topological).
// Readiness: rdy[n] counts completed column-slices (GB == fully written).
// Producer: agent-scope h/c stores -> __syncthreads (vmcnt drain) -> RELEASE add.
// Consumer: ACQUIRE spin on rdy -> __syncthreads -> agent-scope loads.
// Deadlock-free: any wait cycle implies strictly decreasing node indices.
// Requires all 384 blocks co-resident: __launch_bounds__(512,4) => VGPR<=128
// => >=2 blocks/CU => capacity 512 blocks >= 384.
__global__ __launch_bounds__(SCAN_T, 4)
void scan_kernel(const float* __restrict__ Wiouh, const float* __restrict__ biouh,
                 const float* __restrict__ Wfh, const float* __restrict__ bfh,
                 const float* __restrict__ xiou, const float* __restrict__ xf,
                 const int* __restrict__ childOff, const int* __restrict__ childList,
                 int* rdy, float* cbuf, float* out) {
  const int tid = threadIdx.x;
  const int t = blockIdx.x / BPT;
  const int b = blockIdx.x % BPT;
  const int colb = b % GB;
  const int gg = b / GB;
  const int j0 = colb * SLICE;

  const int slot = tid >> 4;        // 0..31 (weights valid for slot<25)
  const int ks = tid & 15;          // 16 k-chunks of 19 (16*19=304, zero-padded)
  const int kk0 = ks * 19;
  const bool dotT = (slot < SLICE); // tid < 400

  const float* xiouT = xiou + (size_t)t * NN * 900;
  const float* xfT = xf + (size_t)t * NN * MEM;
  float* cbufT = cbuf + (size_t)t * NN * MEM;
  float* hT = out + 5 + (size_t)t * NN * MEM;
  const int* coT = childOff + t * (NN + 1);
  const int* clT = childList + t * NN;
  int* rdyT = rdy + t * NN;

  // register-resident weight slices (compile-time indexed only)
  float w0[19], w1[19], w2[19], w3[19];
  if (dotT) {
    const float* r0 = Wiouh + (size_t)(j0 + slot) * MEM;
    const float* r1 = Wiouh + (size_t)(MEM + j0 + slot) * MEM;
    const float* r2 = Wiouh + (size_t)(2 * MEM + j0 + slot) * MEM;
    const float* r3 = Wfh + (size_t)(j0 + slot) * MEM;
    #pragma unroll
    for (int i = 0; i < 19; ++i) {
      const int k = kk0 + i;
      const bool ok = (k < 300);
      const int kc = ok ? k : 0;
      w0[i] = ok ? r0[kc] : 0.f;
      w1[i] = ok ? r1[kc] : 0.f;
      w2[i] = ok ? r2[kc] : 0.f;
      w3[i] = ok ? r3[kc] : 0.f;
    }
  } else {
    #pragma unroll
    for (int i = 0; i < 19; ++i) { w0[i] = w1[i] = w2[i] = w3[i] = 0.f; }
  }

  __shared__ float vb[4][304];
  __shared__ float hsumS[304];
  __shared__ float fcS[SLICE];
  __shared__ float xfS[SLICE];
  __shared__ float cslc[4][SLICE];
  __shared__ float dfS[4][SLICE];
  __shared__ float dIS[SLICE], dOS[SLICE], dUS[SLICE];
  __shared__ int chc[4];
  __shared__ float bI[SLICE], bO[SLICE], bU[SLICE], bF[SLICE];

  if (tid < SLICE) {
    bI[tid] = biouh[j0 + tid];
    bO[tid] = biouh[300 + j0 + tid];
    bU[tid] = biouh[600 + j0 + tid];
    bF[tid] = bfh[j0 + tid];
  }
  __syncthreads();

  for (int n = gg; n < NN; n += NG) {
    const int cS = coT[n];
    const int nchild = coT[n + 1] - cS;

    if (nchild == 0) {
      // leaf: pointwise only
      if (tid < SLICE) {
        const float* xr = xiouT + (size_t)n * 900;
        float i_ = sigmoidf_(xr[j0 + tid] + bI[tid]);
        float o_ = sigmoidf_(xr[300 + j0 + tid] + bO[tid]);
        float u_ = tanhf(xr[600 + j0 + tid] + bU[tid]);
        float c = i_ * u_;
        float h = o_ * tanhf(c);
        agstoref(&cbufT[(size_t)n * MEM + j0 + tid], c);
        agstoref(&hT[(size_t)n * MEM + j0 + tid], h);
      }
      __syncthreads();   // drains the storing threads' vmcnt before the flag
      if (tid == 0)
        __hip_atomic_fetch_add(&rdyT[n], 1, __ATOMIC_RELEASE, __HIP_MEMORY_SCOPE_AGENT);
      continue;
    }

    // internal node: init accumulators + xf cache, spin on children
    for (int e = tid; e < 304; e += SCAN_T) hsumS[e] = 0.f;
    if (tid >= 304 && tid < 304 + SLICE) fcS[tid - 304] = 0.f;
    if (tid >= 352 && tid < 352 + SLICE)
      xfS[tid - 352] = xfT[(size_t)n * MEM + j0 + (tid - 352)];
    for (int i = tid; i < nchild; i += SCAN_T) {
      const int ch = clT[cS + i];
      while (__hip_atomic_load(&rdyT[ch], __ATOMIC_ACQUIRE, __HIP_MEMORY_SCOPE_AGENT) < GB)
        __builtin_amdgcn_s_sleep(1);
    }
    __syncthreads();

    // pull children in chunks of 4: f-gate dot + fcsum, hsum accumulation
    for (int cs = 0; cs < nchild; cs += 4) {
      const int nc = min(4, nchild - cs);
      if (tid < nc) chc[tid] = clT[cS + cs + tid];
      __syncthreads();
      for (int e = tid; e < nc * 304; e += SCAN_T) {
        int cc = e / 304, k = e - cc * 304;
        vb[cc][k] = (k < 300) ? agloadf(&hT[(size_t)chc[cc] * MEM + k]) : 0.f;
      }
      if (tid < nc * SLICE) {
        int cc = tid / SLICE, j = tid % SLICE;
        cslc[cc][j] = agloadf(&cbufT[(size_t)chc[cc] * MEM + j0 + j]);
      }
      __syncthreads();
      if (dotT) {
        for (int cc = 0; cc < nc; ++cc) {
          float a = 0.f;
          #pragma unroll
          for (int i = 0; i < 19; ++i) a += w3[i] * vb[cc][kk0 + i];
          a += __shfl_xor(a, 1); a += __shfl_xor(a, 2);
          a += __shfl_xor(a, 4); a += __shfl_xor(a, 8);
          if (ks == 0) dfS[cc][slot] = a;
        }
      } else {
        for (int k = tid - 400; k < 304; k += 112)
          for (int cc = 0; cc < nc; ++cc) hsumS[k] += vb[cc][k];
      }
      __syncthreads();
      if (tid < nc * SLICE) {
        int cc = tid / SLICE, j = tid % SLICE;
        float f = sigmoidf_(dfS[cc][j] + bF[j] + xfS[j]);
        atomicAdd(&fcS[j], f * cslc[cc][j]);
      }
      __syncthreads();
    }

    // iou dots from accumulated hsum
    if (dotT) {
      float aI = 0.f, aO = 0.f, aU = 0.f;
      #pragma unroll
      for (int i = 0; i < 19; ++i) {
        float v = hsumS[kk0 + i];
        aI += w0[i] * v; aO += w1[i] * v; aU += w2[i] * v;
      }
      aI += __shfl_xor(aI, 1); aO += __shfl_xor(aO, 1); aU += __shfl_xor(aU, 1);
      aI += __shfl_xor(aI, 2); aO += __shfl_xor(aO, 2); aU += __shfl_xor(aU, 2);
      aI += __shfl_xor(aI, 4); aO += __shfl_xor(aO, 4); aU += __shfl_xor(aU, 4);
      aI += __shfl_xor(aI, 8); aO += __shfl_xor(aO, 8); aU += __shfl_xor(aU, 8);
      if (ks == 0) { dIS[slot] = aI; dOS[slot] = aO; dUS[slot] = aU; }
    }
    __syncthreads();
    if (tid < SLICE) {
      const float* xr = xiouT + (size_t)n * 900;
      float i_ = sigmoidf_(dIS[tid] + bI[tid] + xr[j0 + tid]);
      float o_ = sigmoidf_(dOS[tid] + bO[tid] + xr[300 + j0 + tid]);
      float u_ = tanhf(dUS[tid] + bU[tid] + xr[600 + j0 + tid]);
      float c = i_ * u_ + fcS[tid];
      float h = o_ * tanhf(c);
      agstoref(&cbufT[(size_t)n * MEM + j0 + tid], c);
      agstoref(&hT[(size_t)n * MEM + j0 + tid], h);
    }
    __syncthreads();   // drains stores; also guards fcS/dIS reuse next iter
    if (tid == 0)
      __hip_atomic_fetch_add(&rdyT[n], 1, __ATOMIC_RELEASE, __HIP_MEMORY_SCOPE_AGENT);
  }
}

// ---------- K3: similarity head ----------
__global__ __launch_bounds__(256, 1)
void head_kernel(const float* __restrict__ Wwh, const float* __restrict__ bwh,
                 const float* __restrict__ Wwp, const float* __restrict__ bwp,
                 float* out) {
  __shared__ float vd[600];
  __shared__ float hid[200];
  __shared__ float sL[5];
  const int tid = threadIdx.x;
  for (int e = tid; e < 300; e += 256) {
    float lv = out[5 + 1023 * 300 + e];
    float rv = out[5 + 307200 + 1023 * 300 + e];
    vd[e] = lv * rv;
    vd[300 + e] = fabsf(lv - rv);
  }
  __syncthreads();
  if (tid < 200) {
    float acc = bwh[tid];
    const float* wr = Wwh + (size_t)tid * 600;
    for (int k = 0; k < 600; ++k) acc += vd[k] * wr[k];
    hid[tid] = sigmoidf_(acc);
  }
  __syncthreads();
  if (tid < 5) {
    float acc = bwp[tid];
    const float* wr = Wwp + (size_t)tid * 200;
    for (int k = 0; k < 200; ++k) acc += hid[k] * wr[k];
    sL[tid] = acc;
  }
  __syncthreads();
  if (tid == 0) {
    float m = sL[0];
    for (int c = 1; c < 5; ++c) m = fmaxf(m, sL[c]);
    float s = 0.f;
    for (int c = 0; c < 5; ++c) s += expf(sL[c] - m);
    float lz = m + logf(s);
    for (int c = 0; c < 5; ++c) out[c] = sL[c] - lz;
  }
}

extern "C" void kernel_launch(void* const* d_in, const int* in_sizes, int n_in,
                              void* d_out, int out_size, void* d_ws, size_t ws_size,
                              hipStream_t stream) {
  const int* lsent = (const int*)d_in[0];
  const int* lparents = (const int*)d_in[1];
  const int* rsent = (const int*)d_in[2];
  const int* rparents = (const int*)d_in[3];
  const float* emb = (const float*)d_in[5];
  const float* Wioux = (const float*)d_in[6];
  const float* bioux = (const float*)d_in[7];
  const float* Wiouh = (const float*)d_in[8];
  const float* biouh = (const float*)d_in[9];
  const float* Wfx = (const float*)d_in[10];
  const float* bfx = (const float*)d_in[11];
  const float* Wfh = (const float*)d_in[12];
  const float* bfh = (const float*)d_in[13];
  const float* Wwh = (const float*)d_in[14];
  const float* bwh = (const float*)d_in[15];
  const float* Wwp = (const float*)d_in[16];
  const float* bwp = (const float*)d_in[17];
  float* out = (float*)d_out;

  char* ws = (char*)d_ws;
  int* rdy = (int*)(ws);                        // 2048 i = 8192 B (zeroed)
  float* cbuf = (float*)(ws + 8192);            // 2*1024*300 f = 2457600 B
  int* childOff = (int*)(ws + 2465792);         // 2*1025 i = 8200 B
  int* childList = (int*)(ws + 2474112);        // 2048 i = 8192 B
  float* xiou = (float*)(ws + 2482304);         // 2*1024*900 f = 7372800 B
  float* xf = (float*)(ws + 9855104);           // 2*1024*300 f = 2457600 B

  hipMemsetAsync(ws, 0, 8192, stream);
  csr_kernel<<<2, 1024, 0, stream>>>(lparents, rparents, childOff, childList);
  proj_kernel<<<dim3(25, 64), 256, 0, stream>>>(lsent, rsent, emb, Wioux, bioux,
                                                Wfx, bfx, xiou, xf);
  scan_kernel<<<2 * BPT, SCAN_T, 0, stream>>>(Wiouh, biouh, Wfh, bfh, xiou, xf,
                                              childOff, childList, rdy, cbuf, out);
  head_kernel<<<1, 256, 0, stream>>>(Wwh, bwh, Wwp, bwp, out);
}